// Round 3
// baseline (591.611 us; speedup 1.0000x reference)
//
#include <hip/hip_runtime.h>
#include <hip/hip_cooperative_groups.h>

namespace cg = cooperative_groups;

#define LUT_S 33
#define LUT_P (LUT_S*LUT_S*LUT_S)   // 35937
#define CELLS 32768                 // 32^3 cells
#define IMG_H 1080
#define IMG_W 1920
#define TH 256
#define TW 256
#define NBLK 512
#define TPB 256

typedef float f4 __attribute__((ext_vector_type(4)));

// ======================= Backbone megakernel (phased) =======================
// Phases:
//   0: W-resize  img[B*3,1080,1920] -> tmp1[B*3,1080,256]
//   1: H-resize  tmp1 -> thumb[B*3,256,256]
//   2: conv1 3->16 s2 relu (4 oc/thread)        -> c1[B,16,128,128]
//   3: conv2 16->32 s2 relu + row pool (2 oc/t) -> partial[B*32,64]
//   4: head (redundant per block) + blend -> u8 cell records
// Launched EITHER cooperatively once with [0,4] (grid.sync between phases)
// OR as 5 normal launches with [p,p] (kernel boundary provides the sync).
__global__ __launch_bounds__(TPB, 2)
void backbone_mega(const float* __restrict__ img,
                   const float* __restrict__ basis,
                   const float* __restrict__ c1w, const float* __restrict__ c1b,
                   const float* __restrict__ c2w, const float* __restrict__ c2b,
                   const float* __restrict__ dw,  const float* __restrict__ db,
                   float* __restrict__ tmp1, float* __restrict__ thumb,
                   float* __restrict__ c1,   float* __restrict__ partial,
                   uint4* __restrict__ cells, int B,
                   int phase_lo, int phase_hi)
{
    const int tid = threadIdx.x;
    const int bid = blockIdx.x;
    const int nblk = gridDim.x;

    __shared__ float srow[IMG_W];     // phase 0 row stage
    __shared__ float sh_sp[256];      // phase 4 pooled channels (B<=8)
    __shared__ float sh_w[32];        // phase 4 softmax weights

    for (int ph = phase_lo; ph <= phase_hi; ++ph) {
        if (ph != phase_lo) {
            cg::this_grid().sync();   // only reached on cooperative path
        }
        switch (ph) {

        case 0: { // ---------------- W-resize --------------------------------
            int nrows = B * 3 * IMG_H;
            for (int r = bid; r < nrows; r += nblk) {
                const float4* row4 = (const float4*)(img + (size_t)r * IMG_W);
                float4* s4 = (float4*)srow;
                for (int i = tid; i < IMG_W / 4; i += TPB) s4[i] = row4[i];
                __syncthreads();
                int ow = tid;         // TPB == TW == 256
                float sf = (ow + 0.5f) * 7.5f - 0.5f;
                int lo = (int)ceilf(sf - 7.5f); if (lo < 0) lo = 0;
                int hi = (int)floorf(sf + 7.5f); if (hi > IMG_W - 1) hi = IMG_W - 1;
                float acc = 0.f, wsum = 0.f;
                for (int i = lo; i <= hi; ++i) {
                    float w = 1.0f - fabsf(sf - (float)i) * (1.0f / 7.5f);
                    if (w > 0.f) { acc += w * srow[i]; wsum += w; }
                }
                tmp1[(size_t)r * TW + ow] = acc / wsum;
                __syncthreads();      // srow reused next iteration
            }
        } break;

        case 1: { // ---------------- H-resize --------------------------------
            int total = B * 3 * TH * TW;
            for (int e = bid * TPB + tid; e < total; e += nblk * TPB) {
                int ow = e & 255;
                int oh = (e >> 8) & 255;
                int pl = e >> 16;
                float sf = (oh + 0.5f) * 4.21875f - 0.5f;
                int lo = (int)ceilf(sf - 4.21875f); if (lo < 0) lo = 0;
                int hi = (int)floorf(sf + 4.21875f); if (hi > IMG_H - 1) hi = IMG_H - 1;
                const float* col = tmp1 + (size_t)pl * IMG_H * TW + ow;
                float acc = 0.f, wsum = 0.f;
                for (int i = lo; i <= hi; ++i) {
                    float w = 1.0f - fabsf(sf - (float)i) * (1.0f / 4.21875f);
                    if (w > 0.f) { acc += w * col[(size_t)i * TW]; wsum += w; }
                }
                thumb[e] = acc / wsum;
            }
        } break;

        case 2: { // ---------------- conv1 3->16 s2 relu, 4 oc/thread --------
            int total = B * 4 * 128 * 128;
            for (int e = bid * TPB + tid; e < total; e += nblk * TPB) {
                int ow = e & 127;
                int oh = (e >> 7) & 127;
                int g  = (e >> 14) & 3;
                int b  = e >> 16;
                float acc[4];
                #pragma unroll
                for (int j = 0; j < 4; ++j) acc[j] = c1b[g * 4 + j];
                for (int ic = 0; ic < 3; ++ic) {
                    const float* tp = thumb + ((size_t)(b * 3 + ic) << 16);
                    #pragma unroll
                    for (int kh = 0; kh < 3; ++kh) {
                        int ih = oh * 2 + kh;
                        if (ih >= 256) continue;
                        #pragma unroll
                        for (int kw = 0; kw < 3; ++kw) {
                            int iw = ow * 2 + kw;
                            if (iw >= 256) continue;
                            float v = tp[(ih << 8) + iw];
                            #pragma unroll
                            for (int j = 0; j < 4; ++j)
                                acc[j] += v * c1w[((g * 4 + j) * 3 + ic) * 9 + kh * 3 + kw];
                        }
                    }
                }
                size_t o = ((size_t)(b * 16 + g * 4) << 14) + (oh << 7) + ow;
                #pragma unroll
                for (int j = 0; j < 4; ++j)
                    c1[o + ((size_t)j << 14)] = fmaxf(acc[j], 0.f);
            }
        } break;

        case 3: { // -------- conv2 16->32 s2 relu + wave row-pool ------------
            int total = B * 16 * 4096;
            for (int e = bid * TPB + tid; e < total; e += nblk * TPB) {
                int sp = e & 4095;
                int g  = (e >> 12) & 15;
                int b  = e >> 16;
                int ow = sp & 63, oh = sp >> 6;
                float acc[2];
                #pragma unroll
                for (int j = 0; j < 2; ++j) acc[j] = c2b[g * 2 + j];
                for (int ic = 0; ic < 16; ++ic) {
                    const float* ip = c1 + ((size_t)(b * 16 + ic) << 14);
                    #pragma unroll
                    for (int kh = 0; kh < 3; ++kh) {
                        int ih = oh * 2 + kh;
                        if (ih >= 128) continue;
                        #pragma unroll
                        for (int kw = 0; kw < 3; ++kw) {
                            int iw = ow * 2 + kw;
                            if (iw >= 128) continue;
                            float v = ip[(ih << 7) + iw];
                            #pragma unroll
                            for (int j = 0; j < 2; ++j)
                                acc[j] += v * c2w[((g * 2 + j) * 16 + ic) * 9 + kh * 3 + kw];
                        }
                    }
                }
                #pragma unroll
                for (int j = 0; j < 2; ++j) {
                    float val = fmaxf(acc[j], 0.f);
                    #pragma unroll
                    for (int off = 32; off > 0; off >>= 1) val += __shfl_down(val, off, 64);
                    acc[j] = val;
                }
                if ((tid & 63) == 0) {  // wave = full ow row, fixed (b,g,oh)
                    #pragma unroll
                    for (int j = 0; j < 2; ++j)
                        partial[((b * 32 + g * 2 + j) << 6) + oh] = acc[j];
                }
            }
        } break;

        case 4: { // -------- head (redundant per block) + blend --------------
            if (tid < B * 32) {
                const float4* p4 = (const float4*)(partial + (tid << 6));
                float s = 0.f;
                #pragma unroll
                for (int i = 0; i < 16; ++i) {
                    float4 v = p4[i];
                    s += v.x + v.y + v.z + v.w;
                }
                sh_sp[tid] = s * (1.0f / 4096.0f);
            }
            __syncthreads();
            if (tid < B * 3) {
                int b = tid / 3, n = tid - b * 3;
                float acc = db[n];
                for (int ch = 0; ch < 32; ++ch) acc += sh_sp[b * 32 + ch] * dw[ch * 3 + n];
                sh_w[tid] = acc;
            }
            __syncthreads();
            if (tid < B) {
                float a = sh_w[tid * 3 + 0], bb = sh_w[tid * 3 + 1], c = sh_w[tid * 3 + 2];
                float m = fmaxf(a, fmaxf(bb, c));
                float e0 = expf(a - m), e1 = expf(bb - m), e2 = expf(c - m);
                float inv = 1.0f / (e0 + e1 + e2);
                sh_w[tid * 3 + 0] = e0 * inv;
                sh_w[tid * 3 + 1] = e1 * inv;
                sh_w[tid * 3 + 2] = e2 * inv;
            }
            __syncthreads();

            int total = B * CELLS;
            for (int e = bid * TPB + tid; e < total; e += nblk * TPB) {
                int b    = e >> 15;
                int cidx = e & (CELLS - 1);
                int cx = cidx & 31, cy = (cidx >> 5) & 31, cz = cidx >> 10;
                float w0 = sh_w[b * 3 + 0], w1 = sh_w[b * 3 + 1], w2 = sh_w[b * 3 + 2];
                const float* b0 = basis;
                const float* b1 = basis + (size_t)LUT_P * 3;
                const float* b2 = basis + (size_t)2 * LUT_P * 3;
                float v[24];   // [ch*8 + c]
                float mn = 1e30f, mx = -1e30f;
                #pragma unroll
                for (int c = 0; c < 8; ++c) {
                    int dx = c & 1, dy = (c >> 1) & 1, dz = c >> 2;
                    size_t o = (size_t)(((cz + dz) * LUT_S + cy + dy) * LUT_S + cx + dx) * 3;
                    #pragma unroll
                    for (int ch = 0; ch < 3; ++ch) {
                        float val = w0 * b0[o + ch] + w1 * b1[o + ch] + w2 * b2[o + ch];
                        v[ch * 8 + c] = val;
                        mn = fminf(mn, val); mx = fmaxf(mx, val);
                    }
                }
                float range = mx - mn;
                float inv = (range > 1e-20f) ? 255.0f / range : 0.0f;
                float scale = range * (1.0f / 255.0f);
                unsigned int d[6];
                #pragma unroll
                for (int k = 0; k < 6; ++k) {
                    unsigned int pk = 0;
                    #pragma unroll
                    for (int j = 0; j < 4; ++j) {
                        float q = (v[k * 4 + j] - mn) * inv;
                        int qi = (int)rintf(q);
                        qi = qi < 0 ? 0 : (qi > 255 ? 255 : qi);
                        pk |= ((unsigned int)qi) << (8 * j);
                    }
                    d[k] = pk;
                }
                uint4* outp = cells + ((size_t)e << 1);
                outp[0] = make_uint4(d[0], d[1], d[2], d[3]);
                outp[1] = make_uint4(d[4], d[5], __float_as_uint(scale), __float_as_uint(mn));
            }
        } break;
        }
    }
}

// ---------------- Kernel F: apply LUT via u8 cell records, 4 px / thread ----
// (unchanged — control group for counters)
__device__ __forceinline__ float trilerp_u8(unsigned int lo, unsigned int hi,
                                            float fx, float fy, float fz) {
    float q000 = (float)(lo & 0xffu);
    float q100 = (float)((lo >> 8) & 0xffu);
    float q010 = (float)((lo >> 16) & 0xffu);
    float q110 = (float)((lo >> 24) & 0xffu);
    float q001 = (float)(hi & 0xffu);
    float q101 = (float)((hi >> 8) & 0xffu);
    float q011 = (float)((hi >> 16) & 0xffu);
    float q111 = (float)((hi >> 24) & 0xffu);
    float a0 = q000 + fx * (q100 - q000);
    float a1 = q010 + fx * (q110 - q010);
    float b0 = q001 + fx * (q101 - q001);
    float b1 = q011 + fx * (q111 - q011);
    float c0 = a0 + fy * (a1 - a0);
    float c1 = b0 + fy * (b1 - b0);
    return c0 + fz * (c1 - c0);
}

__global__ __launch_bounds__(256)
void apply_lut_kernel(const float* __restrict__ img,
                      const uint4* __restrict__ cells,
                      float* __restrict__ out, int total_quads) {
    const int P  = IMG_H * IMG_W;       // 2,073,600
    const int QP = P / 4;               // 518,400
    int t = blockIdx.x * blockDim.x + threadIdx.x;
    if (t >= total_quads) return;
    int b = t / QP;
    int q = t - b * QP;
    const uint4* cbase = cells + ((size_t)b * CELLS << 1);
    size_t base = (size_t)b * 3 * P + (size_t)q * 4;
    f4 R  = *(const f4*)(img + base);
    f4 G  = *(const f4*)(img + base + P);
    f4 Bl = *(const f4*)(img + base + 2 * (size_t)P);

    int cidx[4]; float fx[4], fy[4], fz[4];
    #pragma unroll
    for (int k = 0; k < 4; ++k) {
        float pr = fminf(fmaxf(R[k], 0.f), 1.f) * (float)(LUT_S - 1);
        float pg = fminf(fmaxf(G[k], 0.f), 1.f) * (float)(LUT_S - 1);
        float pb = fminf(fmaxf(Bl[k], 0.f), 1.f) * (float)(LUT_S - 1);
        int ix = (int)pr; if (ix > LUT_S - 2) ix = LUT_S - 2;
        int iy = (int)pg; if (iy > LUT_S - 2) iy = LUT_S - 2;
        int iz = (int)pb; if (iz > LUT_S - 2) iz = LUT_S - 2;
        fx[k] = pr - (float)ix;
        fy[k] = pg - (float)iy;
        fz[k] = pb - (float)iz;
        cidx[k] = (iz << 10) | (iy << 5) | ix;   // x<-R, y<-G, z<-B
    }
    uint4 A[4], Bq[4];
    #pragma unroll
    for (int k = 0; k < 4; ++k) {
        const uint4* cp = cbase + ((size_t)cidx[k] << 1);
        A[k]  = cp[0];
        Bq[k] = cp[1];
    }
    f4 Ro, Go, Bo;
    #pragma unroll
    for (int k = 0; k < 4; ++k) {
        float scale = __uint_as_float(Bq[k].z);
        float offs  = __uint_as_float(Bq[k].w);
        float tr = trilerp_u8(A[k].x, A[k].y, fx[k], fy[k], fz[k]);
        float tg = trilerp_u8(A[k].z, A[k].w, fx[k], fy[k], fz[k]);
        float tb = trilerp_u8(Bq[k].x, Bq[k].y, fx[k], fy[k], fz[k]);
        Ro[k] = fminf(fmaxf(tr * scale + offs, 0.f), 1.f);
        Go[k] = fminf(fmaxf(tg * scale + offs, 0.f), 1.f);
        Bo[k] = fminf(fmaxf(tb * scale + offs, 0.f), 1.f);
    }
    __builtin_nontemporal_store(Ro, (f4*)(out + base));
    __builtin_nontemporal_store(Go, (f4*)(out + base + P));
    __builtin_nontemporal_store(Bo, (f4*)(out + base + 2 * (size_t)P));
}

extern "C" void kernel_launch(void* const* d_in, const int* in_sizes, int n_in,
                              void* d_out, int out_size, void* d_ws, size_t ws_size,
                              hipStream_t stream) {
    const float* img     = (const float*)d_in[0];
    const float* basis   = (const float*)d_in[1];
    const float* conv1_w = (const float*)d_in[2];
    const float* conv1_b = (const float*)d_in[3];
    const float* conv2_w = (const float*)d_in[4];
    const float* conv2_b = (const float*)d_in[5];
    const float* dense_w = (const float*)d_in[6];
    const float* dense_b = (const float*)d_in[7];
    float* out = (float*)d_out;

    const size_t P = (size_t)IMG_H * IMG_W;
    int B = (int)(in_sizes[0] / (3 * P));   // 4

    // workspace layout (floats)
    float* ws = (float*)d_ws;
    size_t off = 0;
    float* tmp1    = ws + off; off += (size_t)B * 3 * IMG_H * TW;
    float* thumb   = ws + off; off += (size_t)B * 3 * TH * TW;
    float* c1      = ws + off; off += (size_t)B * 16 * 128 * 128;
    float* partial = ws + off; off += (size_t)B * 32 * 64;
    off = (off + 3) & ~(size_t)3;                                  // 16B align
    uint4* cells   = (uint4*)(ws + off); off += (size_t)B * CELLS * 8;

    {   // cooperative backbone (1 launch); fallback: 5 phase launches
        int p_lo = 0, p_hi = 4;
        void* kargs[] = {
            (void*)&img, (void*)&basis,
            (void*)&conv1_w, (void*)&conv1_b,
            (void*)&conv2_w, (void*)&conv2_b,
            (void*)&dense_w, (void*)&dense_b,
            (void*)&tmp1, (void*)&thumb, (void*)&c1, (void*)&partial,
            (void*)&cells, (void*)&B, (void*)&p_lo, (void*)&p_hi
        };
        hipError_t cerr = hipLaunchCooperativeKernel(backbone_mega, dim3(NBLK), dim3(TPB),
                                                     kargs, 0, stream);
        if (cerr != hipSuccess) {
            (void)hipGetLastError();   // clear sticky error
            for (int ph = 0; ph < 5; ++ph) {
                backbone_mega<<<NBLK, TPB, 0, stream>>>(
                    img, basis, conv1_w, conv1_b, conv2_w, conv2_b,
                    dense_w, dense_b, tmp1, thumb, c1, partial,
                    cells, B, ph, ph);
            }
        }
    }
    {   // apply
        int total = B * (int)(P / 4);
        apply_lut_kernel<<<(total + 255) / 256, 256, 0, stream>>>(img, cells, out, total);
    }
}

// Round 4
// 279.798 us; speedup vs baseline: 2.1144x; 2.1144x over previous
//
#include <hip/hip_runtime.h>

#define LUT_S 33
#define LUT_P (LUT_S*LUT_S*LUT_S)   // 35937
#define CELLS 32768                 // 32^3 cells
#define IMG_H 1080
#define IMG_W 1920
#define TH 256
#define TW 256

typedef float f4 __attribute__((ext_vector_type(4)));

// ---------------- Kernel A: W-resize via LDS row staging --------------------
// img [B*3, 1080, 1920] -> tmp [B*3, 1080, 256]; one block per row.
__global__ __launch_bounds__(256)
void resize_w_kernel(const float* __restrict__ img, float* __restrict__ tmp) {
    __shared__ float srow[IMG_W];
    int r = blockIdx.x;                       // over B*3*1080 rows
    const float4* row4 = (const float4*)(img + (size_t)r * IMG_W);
    float4* s4 = (float4*)srow;
    for (int i = threadIdx.x; i < IMG_W / 4; i += 256) s4[i] = row4[i];
    __syncthreads();
    int ow = threadIdx.x;
    const float kscale = 7.5f;                // 1920/256
    float sf = (ow + 0.5f) * 7.5f - 0.5f;
    int lo = (int)ceilf(sf - kscale); if (lo < 0) lo = 0;
    int hi = (int)floorf(sf + kscale); if (hi > IMG_W - 1) hi = IMG_W - 1;
    float acc = 0.f, wsum = 0.f;
    for (int i = lo; i <= hi; ++i) {
        float w = 1.0f - fabsf(sf - (float)i) * (1.0f / 7.5f);
        if (w > 0.f) { acc += w * srow[i]; wsum += w; }
    }
    tmp[(size_t)r * TW + ow] = acc / wsum;
}

// ---------------- Kernel B: H-resize (kscale=4.21875), coalesced ------------
// tmp [B*3, 1080, 256] -> thumb [B*3, 256, 256]
__global__ void resize_h_kernel(const float* __restrict__ tmp,
                                float* __restrict__ thumb, int total) {
    int e = blockIdx.x * blockDim.x + threadIdx.x;
    if (e >= total) return;
    int ow = e & 255;
    int oh = (e >> 8) & 255;
    int pl = e >> 16;           // plane over B*3
    const float kscale = 4.21875f;  // 1080/256
    float sf = (oh + 0.5f) * 4.21875f - 0.5f;
    int lo = (int)ceilf(sf - kscale); if (lo < 0) lo = 0;
    int hi = (int)floorf(sf + kscale); if (hi > IMG_H - 1) hi = IMG_H - 1;
    const float* col = tmp + (size_t)pl * IMG_H * TW + ow;
    float acc = 0.f, wsum = 0.f;
    for (int i = lo; i <= hi; ++i) {
        float w = 1.0f - fabsf(sf - (float)i) * (1.0f / 4.21875f);
        if (w > 0.f) { acc += w * col[(size_t)i * TW]; wsum += w; }
    }
    thumb[e] = acc / wsum;
}

// ------- Kernel C1: conv1 3->16 s2 SAME(pad_lo=0) relu, 4 oc / thread -------
// thumb [B,3,256,256] -> c1 [B,16,128,128]
__global__ void conv1_kernel(const float* __restrict__ thumb,
                             const float* __restrict__ w,
                             const float* __restrict__ bias,
                             float* __restrict__ out, int total) {
    int e = blockIdx.x * blockDim.x + threadIdx.x;
    if (e >= total) return;
    int ow = e & 127;
    int oh = (e >> 7) & 127;
    int g  = (e >> 14) & 3;                   // oc group of 4 (wave-uniform)
    int b  = e >> 16;
    float acc[4];
    #pragma unroll
    for (int j = 0; j < 4; ++j) acc[j] = bias[g * 4 + j];
    for (int ic = 0; ic < 3; ++ic) {
        const float* tp = thumb + ((size_t)(b * 3 + ic) << 16);
        #pragma unroll
        for (int kh = 0; kh < 3; ++kh) {
            int ih = oh * 2 + kh;
            if (ih >= 256) continue;
            #pragma unroll
            for (int kw = 0; kw < 3; ++kw) {
                int iw = ow * 2 + kw;
                if (iw >= 256) continue;
                float v = tp[(ih << 8) + iw];
                #pragma unroll
                for (int j = 0; j < 4; ++j)
                    acc[j] += v * w[((g * 4 + j) * 3 + ic) * 9 + kh * 3 + kw];
            }
        }
    }
    size_t o = ((size_t)(b * 16 + g * 4) << 14) + (oh << 7) + ow;
    #pragma unroll
    for (int j = 0; j < 4; ++j)
        out[o + ((size_t)j << 14)] = fmaxf(acc[j], 0.f);
}

// -- Kernel C2+D1: conv2 16->32 s2 relu + pool, 2 oc / thread, wave-reduce ---
// c1 [B,16,128,128] -> partial [B*32, 64]
__global__ void conv2_pool_kernel(const float* __restrict__ c1,
                                  const float* __restrict__ w,
                                  const float* __restrict__ bias,
                                  float* __restrict__ partial, int total) {
    int e = blockIdx.x * blockDim.x + threadIdx.x;
    if (e >= total) return;
    int sp = e & 4095;                        // oh*64+ow
    int g  = (e >> 12) & 15;                  // oc pair (wave-uniform)
    int b  = e >> 16;
    int ow = sp & 63, oh = sp >> 6;
    float acc[2];
    #pragma unroll
    for (int j = 0; j < 2; ++j) acc[j] = bias[g * 2 + j];
    for (int ic = 0; ic < 16; ++ic) {
        const float* ip = c1 + ((size_t)(b * 16 + ic) << 14);
        #pragma unroll
        for (int kh = 0; kh < 3; ++kh) {
            int ih = oh * 2 + kh;
            if (ih >= 128) continue;
            #pragma unroll
            for (int kw = 0; kw < 3; ++kw) {
                int iw = ow * 2 + kw;
                if (iw >= 128) continue;
                float v = ip[(ih << 7) + iw];
                #pragma unroll
                for (int j = 0; j < 2; ++j)
                    acc[j] += v * w[((g * 2 + j) * 16 + ic) * 9 + kh * 3 + kw];
            }
        }
    }
    #pragma unroll
    for (int j = 0; j < 2; ++j) {
        float val = fmaxf(acc[j], 0.f);
        #pragma unroll
        for (int off = 32; off > 0; off >>= 1) val += __shfl_down(val, off, 64);
        acc[j] = val;
    }
    // wave = 64 consecutive e -> full ow row, fixed (b,g,oh)
    if ((threadIdx.x & 63) == 0) {
        #pragma unroll
        for (int j = 0; j < 2; ++j)
            partial[((b * 32 + g * 2 + j) << 6) + oh] = acc[j];
    }
}

// --- Kernel E: fused head (redundant per block) + blend -> 32B cell records -
// Record (32 B, uint4 x2): bytes 0-7 r corners c0..7 (c=dz*4+dy*2+dx),
// 8-15 g, 16-23 b, dword6 = scale(f32), dword7 = offset(f32).
__global__ __launch_bounds__(256)
void blend_cells_kernel(const float* __restrict__ basis,
                        const float* __restrict__ partial,
                        const float* __restrict__ dw,
                        const float* __restrict__ db,
                        uint4* __restrict__ cells, int B, int total) {
    __shared__ float sh_sp[256];
    __shared__ float sh_w[32];
    int tid = threadIdx.x;
    // ---- head, recomputed per block (reads B*32*64 floats = 32 KB, L2) ----
    if (tid < B * 32) {
        const float4* p4 = (const float4*)(partial + (tid << 6));
        float s = 0.f;
        #pragma unroll
        for (int i = 0; i < 16; ++i) {
            float4 v = p4[i];
            s += v.x + v.y + v.z + v.w;
        }
        sh_sp[tid] = s * (1.0f / 4096.0f);
    }
    __syncthreads();
    if (tid < B * 3) {
        int b = tid / 3, n = tid - b * 3;
        float acc = db[n];
        for (int ch = 0; ch < 32; ++ch) acc += sh_sp[b * 32 + ch] * dw[ch * 3 + n];
        sh_w[tid] = acc;
    }
    __syncthreads();
    if (tid < B) {
        float a = sh_w[tid * 3 + 0], bb = sh_w[tid * 3 + 1], c = sh_w[tid * 3 + 2];
        float m = fmaxf(a, fmaxf(bb, c));
        float e0 = expf(a - m), e1 = expf(bb - m), e2 = expf(c - m);
        float inv = 1.0f / (e0 + e1 + e2);
        sh_w[tid * 3 + 0] = e0 * inv;
        sh_w[tid * 3 + 1] = e1 * inv;
        sh_w[tid * 3 + 2] = e2 * inv;
    }
    __syncthreads();

    int e = blockIdx.x * blockDim.x + tid;
    if (e >= total) return;
    int b    = e >> 15;
    int cidx = e & (CELLS - 1);
    int cx = cidx & 31, cy = (cidx >> 5) & 31, cz = cidx >> 10;
    float w0 = sh_w[b * 3 + 0], w1 = sh_w[b * 3 + 1], w2 = sh_w[b * 3 + 2];
    const float* b0 = basis;
    const float* b1 = basis + (size_t)LUT_P * 3;
    const float* b2 = basis + (size_t)2 * LUT_P * 3;
    float v[24];   // [ch*8 + c]
    float mn = 1e30f, mx = -1e30f;
    #pragma unroll
    for (int c = 0; c < 8; ++c) {
        int dx = c & 1, dy = (c >> 1) & 1, dz = c >> 2;
        size_t o = (size_t)(((cz + dz) * LUT_S + cy + dy) * LUT_S + cx + dx) * 3;
        #pragma unroll
        for (int ch = 0; ch < 3; ++ch) {
            float val = w0 * b0[o + ch] + w1 * b1[o + ch] + w2 * b2[o + ch];
            v[ch * 8 + c] = val;
            mn = fminf(mn, val); mx = fmaxf(mx, val);
        }
    }
    float range = mx - mn;
    float inv = (range > 1e-20f) ? 255.0f / range : 0.0f;
    float scale = range * (1.0f / 255.0f);
    unsigned int d[6];
    #pragma unroll
    for (int k = 0; k < 6; ++k) {
        unsigned int pk = 0;
        #pragma unroll
        for (int j = 0; j < 4; ++j) {
            float q = (v[k * 4 + j] - mn) * inv;
            int qi = (int)rintf(q);
            qi = qi < 0 ? 0 : (qi > 255 ? 255 : qi);
            pk |= ((unsigned int)qi) << (8 * j);
        }
        d[k] = pk;
    }
    uint4* outp = cells + ((size_t)e << 1);
    outp[0] = make_uint4(d[0], d[1], d[2], d[3]);
    outp[1] = make_uint4(d[4], d[5], __float_as_uint(scale), __float_as_uint(mn));
}

// ---------------- Kernel F: apply LUT via u8 cell records, 4 px / thread ----
// XCD-swizzled blocks (contiguous quad chunk per XCD -> per-XCD L2 holds ~1
// image's 1MB cell table), NT img loads (don't evict cells), NT stores.
__device__ __forceinline__ float trilerp_u8(unsigned int lo, unsigned int hi,
                                            float fx, float fy, float fz) {
    float q000 = (float)(lo & 0xffu);
    float q100 = (float)((lo >> 8) & 0xffu);
    float q010 = (float)((lo >> 16) & 0xffu);
    float q110 = (float)((lo >> 24) & 0xffu);
    float q001 = (float)(hi & 0xffu);
    float q101 = (float)((hi >> 8) & 0xffu);
    float q011 = (float)((hi >> 16) & 0xffu);
    float q111 = (float)((hi >> 24) & 0xffu);
    float a0 = q000 + fx * (q100 - q000);
    float a1 = q010 + fx * (q110 - q010);
    float b0 = q001 + fx * (q101 - q001);
    float b1 = q011 + fx * (q111 - q011);
    float c0 = a0 + fy * (a1 - a0);
    float c1 = b0 + fy * (b1 - b0);
    return c0 + fz * (c1 - c0);
}

__global__ __launch_bounds__(256)
void apply_lut_kernel(const float* __restrict__ img,
                      const uint4* __restrict__ cells,
                      float* __restrict__ out, int total_quads, int nblk) {
    const int P  = IMG_H * IMG_W;       // 2,073,600
    const int QP = P / 4;               // 518,400
    // ---- bijective XCD swizzle (m204): XCD k gets a contiguous block range
    int orig = blockIdx.x;
    int qd = nblk >> 3, rm = nblk & 7;
    int xcd = orig & 7, idx = orig >> 3;
    int base = (xcd < rm) ? xcd * (qd + 1) : rm * (qd + 1) + (xcd - rm) * qd;
    int bid = base + idx;
    int t = bid * 256 + (int)threadIdx.x;
    if (t >= total_quads) return;
    int b = t / QP;
    int q = t - b * QP;
    const uint4* cbase = cells + ((size_t)b * CELLS << 1);
    size_t base_e = (size_t)b * 3 * P + (size_t)q * 4;
    f4 R  = __builtin_nontemporal_load((const f4*)(img + base_e));
    f4 G  = __builtin_nontemporal_load((const f4*)(img + base_e + P));
    f4 Bl = __builtin_nontemporal_load((const f4*)(img + base_e + 2 * (size_t)P));

    int cidx[4]; float fx[4], fy[4], fz[4];
    #pragma unroll
    for (int k = 0; k < 4; ++k) {
        float pr = fminf(fmaxf(R[k], 0.f), 1.f) * (float)(LUT_S - 1);
        float pg = fminf(fmaxf(G[k], 0.f), 1.f) * (float)(LUT_S - 1);
        float pb = fminf(fmaxf(Bl[k], 0.f), 1.f) * (float)(LUT_S - 1);
        int ix = (int)pr; if (ix > LUT_S - 2) ix = LUT_S - 2;
        int iy = (int)pg; if (iy > LUT_S - 2) iy = LUT_S - 2;
        int iz = (int)pb; if (iz > LUT_S - 2) iz = LUT_S - 2;
        fx[k] = pr - (float)ix;
        fy[k] = pg - (float)iy;
        fz[k] = pb - (float)iz;
        cidx[k] = (iz << 10) | (iy << 5) | ix;   // x<-R, y<-G, z<-B
    }
    // Issue all 8 gathers before consuming any (memory-level parallelism).
    uint4 A[4], Bq[4];
    #pragma unroll
    for (int k = 0; k < 4; ++k) {
        const uint4* cp = cbase + ((size_t)cidx[k] << 1);
        A[k]  = cp[0];
        Bq[k] = cp[1];
    }
    f4 Ro, Go, Bo;
    #pragma unroll
    for (int k = 0; k < 4; ++k) {
        float scale = __uint_as_float(Bq[k].z);
        float offs  = __uint_as_float(Bq[k].w);
        float tr = trilerp_u8(A[k].x, A[k].y, fx[k], fy[k], fz[k]);
        float tg = trilerp_u8(A[k].z, A[k].w, fx[k], fy[k], fz[k]);
        float tb = trilerp_u8(Bq[k].x, Bq[k].y, fx[k], fy[k], fz[k]);
        Ro[k] = fminf(fmaxf(tr * scale + offs, 0.f), 1.f);
        Go[k] = fminf(fmaxf(tg * scale + offs, 0.f), 1.f);
        Bo[k] = fminf(fmaxf(tb * scale + offs, 0.f), 1.f);
    }
    __builtin_nontemporal_store(Ro, (f4*)(out + base_e));
    __builtin_nontemporal_store(Go, (f4*)(out + base_e + P));
    __builtin_nontemporal_store(Bo, (f4*)(out + base_e + 2 * (size_t)P));
}

extern "C" void kernel_launch(void* const* d_in, const int* in_sizes, int n_in,
                              void* d_out, int out_size, void* d_ws, size_t ws_size,
                              hipStream_t stream) {
    const float* img     = (const float*)d_in[0];
    const float* basis   = (const float*)d_in[1];
    const float* conv1_w = (const float*)d_in[2];
    const float* conv1_b = (const float*)d_in[3];
    const float* conv2_w = (const float*)d_in[4];
    const float* conv2_b = (const float*)d_in[5];
    const float* dense_w = (const float*)d_in[6];
    const float* dense_b = (const float*)d_in[7];
    float* out = (float*)d_out;

    const size_t P = (size_t)IMG_H * IMG_W;
    int B = (int)(in_sizes[0] / (3 * P));   // 4

    // workspace layout (floats)
    float* ws = (float*)d_ws;
    size_t off = 0;
    float* tmp1    = ws + off; off += (size_t)B * 3 * IMG_H * TW;
    float* thumb   = ws + off; off += (size_t)B * 3 * TH * TW;
    float* c1      = ws + off; off += (size_t)B * 16 * 128 * 128;
    float* partial = ws + off; off += (size_t)B * 32 * 64;
    off = (off + 3) & ~(size_t)3;                                  // 16B align
    uint4* cells   = (uint4*)(ws + off); off += (size_t)B * CELLS * 8;

    const int TPB = 256;
    {   // A: W-resize (one block per row)
        resize_w_kernel<<<B * 3 * IMG_H, TPB, 0, stream>>>(img, tmp1);
    }
    {   // B: H-resize
        int total = B * 3 * TH * TW;
        resize_h_kernel<<<(total + TPB - 1) / TPB, TPB, 0, stream>>>(tmp1, thumb, total);
    }
    {   // C1: 4 oc / thread, 4 groups
        int total = B * 4 * 128 * 128;
        conv1_kernel<<<(total + TPB - 1) / TPB, TPB, 0, stream>>>(thumb, conv1_w, conv1_b, c1, total);
    }
    {   // C2 + pool: 2 oc / thread, 16 groups
        int total = B * 16 * 4096;
        conv2_pool_kernel<<<(total + TPB - 1) / TPB, TPB, 0, stream>>>(c1, conv2_w, conv2_b, partial, total);
    }
    {   // E: fused head + blend -> u8 cell records
        int total = B * CELLS;
        blend_cells_kernel<<<(total + TPB - 1) / TPB, TPB, 0, stream>>>(
            basis, partial, dense_w, dense_b, cells, B, total);
    }
    {   // F: apply (XCD-swizzled)
        int total = B * (int)(P / 4);
        int nblk = (total + TPB - 1) / TPB;
        apply_lut_kernel<<<nblk, TPB, 0, stream>>>(img, cells, out, total, nblk);
    }
}

// Round 5
// 272.085 us; speedup vs baseline: 2.1744x; 1.0284x over previous
//
#include <hip/hip_runtime.h>

#define LUT_S 33
#define LUT_P (LUT_S*LUT_S*LUT_S)   // 35937
#define CELLS 32768                 // 32^3 cells
#define IMG_H 1080
#define IMG_W 1920
#define TH 256
#define TW 256

typedef float f4 __attribute__((ext_vector_type(4)));
// dword-aligned vector types (addresses here are only 4/8-byte aligned)
typedef float f4a __attribute__((ext_vector_type(4), aligned(4)));
typedef float f2a __attribute__((ext_vector_type(2), aligned(4)));

// ---------------- Kernel A: W-resize via LDS row staging --------------------
// img [B*3, 1080, 1920] -> tmp [B*3, 1080, 256]; one block per row.
__global__ __launch_bounds__(256)
void resize_w_kernel(const float* __restrict__ img, float* __restrict__ tmp) {
    __shared__ float srow[IMG_W];
    int r = blockIdx.x;                       // over B*3*1080 rows
    const float4* row4 = (const float4*)(img + (size_t)r * IMG_W);
    float4* s4 = (float4*)srow;
    for (int i = threadIdx.x; i < IMG_W / 4; i += 256) s4[i] = row4[i];
    __syncthreads();
    int ow = threadIdx.x;
    const float kscale = 7.5f;                // 1920/256
    float sf = (ow + 0.5f) * 7.5f - 0.5f;
    int lo = (int)ceilf(sf - kscale); if (lo < 0) lo = 0;
    int hi = (int)floorf(sf + kscale); if (hi > IMG_W - 1) hi = IMG_W - 1;
    float acc = 0.f, wsum = 0.f;
    for (int i = lo; i <= hi; ++i) {
        float w = 1.0f - fabsf(sf - (float)i) * (1.0f / 7.5f);
        if (w > 0.f) { acc += w * srow[i]; wsum += w; }
    }
    tmp[(size_t)r * TW + ow] = acc / wsum;
}

// ---------------- Kernel B: H-resize (kscale=4.21875), coalesced ------------
// tmp [B*3, 1080, 256] -> thumb [B*3, 256, 256]
__global__ __launch_bounds__(256)
void resize_h_kernel(const float* __restrict__ tmp,
                     float* __restrict__ thumb, int total) {
    int e = blockIdx.x * blockDim.x + threadIdx.x;
    if (e >= total) return;
    int ow = e & 255;
    int oh = (e >> 8) & 255;
    int pl = e >> 16;           // plane over B*3
    const float kscale = 4.21875f;  // 1080/256
    float sf = (oh + 0.5f) * 4.21875f - 0.5f;
    int lo = (int)ceilf(sf - kscale); if (lo < 0) lo = 0;
    int hi = (int)floorf(sf + kscale); if (hi > IMG_H - 1) hi = IMG_H - 1;
    const float* col = tmp + (size_t)pl * IMG_H * TW + ow;
    float acc = 0.f, wsum = 0.f;
    for (int i = lo; i <= hi; ++i) {
        float w = 1.0f - fabsf(sf - (float)i) * (1.0f / 4.21875f);
        if (w > 0.f) { acc += w * col[(size_t)i * TW]; wsum += w; }
    }
    thumb[e] = acc / wsum;
}

// ------- Kernel C1: conv1 3->16 s2 SAME(pad_lo=0) relu, 4 oc / thread -------
// thumb [B,3,256,256] -> c1 [B,16,128,128]; float2 loads (18 vs 27 VMEM).
__global__ __launch_bounds__(256)
void conv1_kernel(const float* __restrict__ thumb,
                  const float* __restrict__ w,
                  const float* __restrict__ bias,
                  float* __restrict__ out, int total) {
    int e = blockIdx.x * blockDim.x + threadIdx.x;
    if (e >= total) return;
    int ow = e & 127;
    int oh = (e >> 7) & 127;
    int g  = (e >> 14) & 3;                   // oc group of 4 (wave-uniform)
    int b  = e >> 16;
    float acc[4];
    #pragma unroll
    for (int j = 0; j < 4; ++j) acc[j] = bias[g * 4 + j];
    for (int ic = 0; ic < 3; ++ic) {
        const float* tp = thumb + ((size_t)(b * 3 + ic) << 16);
        #pragma unroll
        for (int kh = 0; kh < 3; ++kh) {
            int ih = oh * 2 + kh;
            if (ih >= 256) continue;          // bottom pad (oh=127,kh=2)
            const float* rp = tp + (ih << 8) + (ow << 1);
            f2a p01 = *(const f2a*)rp;        // iw = 2ow, 2ow+1 (always in)
            float p2 = (ow < 127) ? rp[2] : 0.f;  // right pad: 0-tap == skip
            #pragma unroll
            for (int j = 0; j < 4; ++j) {
                const float* wp = w + ((g * 4 + j) * 3 + ic) * 9 + kh * 3;
                acc[j] += p01.x * wp[0] + p01.y * wp[1] + p2 * wp[2];
            }
        }
    }
    size_t o = ((size_t)(b * 16 + g * 4) << 14) + (oh << 7) + ow;
    #pragma unroll
    for (int j = 0; j < 4; ++j)
        out[o + ((size_t)j << 14)] = fmaxf(acc[j], 0.f);
}

// -- Kernel C2+D1: conv2 16->32 s2 relu + pool, 2 oc / thread, wave-reduce ---
// c1 [B,16,128,128] -> partial [B*32, 64]; float2 loads (96 vs 144 VMEM).
__global__ __launch_bounds__(256)
void conv2_pool_kernel(const float* __restrict__ c1,
                       const float* __restrict__ w,
                       const float* __restrict__ bias,
                       float* __restrict__ partial, int total) {
    int e = blockIdx.x * blockDim.x + threadIdx.x;
    if (e >= total) return;
    int sp = e & 4095;                        // oh*64+ow
    int g  = (e >> 12) & 15;                  // oc pair (wave-uniform)
    int b  = e >> 16;
    int ow = sp & 63, oh = sp >> 6;
    float acc[2];
    #pragma unroll
    for (int j = 0; j < 2; ++j) acc[j] = bias[g * 2 + j];
    for (int ic = 0; ic < 16; ++ic) {
        const float* ip = c1 + ((size_t)(b * 16 + ic) << 14);
        #pragma unroll
        for (int kh = 0; kh < 3; ++kh) {
            int ih = oh * 2 + kh;
            if (ih >= 128) continue;          // bottom pad (oh=63,kh=2)
            const float* rp = ip + (ih << 7) + (ow << 1);
            f2a p01 = *(const f2a*)rp;        // iw = 2ow, 2ow+1
            float p2 = (ow < 63) ? rp[2] : 0.f;   // right pad
            #pragma unroll
            for (int j = 0; j < 2; ++j) {
                const float* wp = w + ((g * 2 + j) * 16 + ic) * 9 + kh * 3;
                acc[j] += p01.x * wp[0] + p01.y * wp[1] + p2 * wp[2];
            }
        }
    }
    #pragma unroll
    for (int j = 0; j < 2; ++j) {
        float val = fmaxf(acc[j], 0.f);
        #pragma unroll
        for (int off = 32; off > 0; off >>= 1) val += __shfl_down(val, off, 64);
        acc[j] = val;
    }
    // wave = 64 consecutive e -> full ow row, fixed (b,g,oh)
    if ((threadIdx.x & 63) == 0) {
        #pragma unroll
        for (int j = 0; j < 2; ++j)
            partial[((b * 32 + g * 2 + j) << 6) + oh] = acc[j];
    }
}

// --- Kernel E: fused head (redundant per block) + blend -> 32B cell records -
// Vectorized: each cell corner-pair row = 6 contiguous floats -> f4+f2 loads;
// 24 VMEM/thread vs 72 scalar.
__global__ __launch_bounds__(256)
void blend_cells_kernel(const float* __restrict__ basis,
                        const float* __restrict__ partial,
                        const float* __restrict__ dw,
                        const float* __restrict__ db,
                        uint4* __restrict__ cells, int B, int total) {
    __shared__ float sh_sp[256];
    __shared__ float sh_w[32];
    int tid = threadIdx.x;
    // ---- head, recomputed per block (reads B*32*64 floats = 32 KB, L2) ----
    if (tid < B * 32) {
        const float4* p4 = (const float4*)(partial + (tid << 6));
        float s = 0.f;
        #pragma unroll
        for (int i = 0; i < 16; ++i) {
            float4 v = p4[i];
            s += v.x + v.y + v.z + v.w;
        }
        sh_sp[tid] = s * (1.0f / 4096.0f);
    }
    __syncthreads();
    if (tid < B * 3) {
        int b = tid / 3, n = tid - b * 3;
        float acc = db[n];
        for (int ch = 0; ch < 32; ++ch) acc += sh_sp[b * 32 + ch] * dw[ch * 3 + n];
        sh_w[tid] = acc;
    }
    __syncthreads();
    if (tid < B) {
        float a = sh_w[tid * 3 + 0], bb = sh_w[tid * 3 + 1], c = sh_w[tid * 3 + 2];
        float m = fmaxf(a, fmaxf(bb, c));
        float e0 = expf(a - m), e1 = expf(bb - m), e2 = expf(c - m);
        float inv = 1.0f / (e0 + e1 + e2);
        sh_w[tid * 3 + 0] = e0 * inv;
        sh_w[tid * 3 + 1] = e1 * inv;
        sh_w[tid * 3 + 2] = e2 * inv;
    }
    __syncthreads();

    int e = blockIdx.x * blockDim.x + tid;
    if (e >= total) return;
    int b    = e >> 15;
    int cidx = e & (CELLS - 1);
    int cx = cidx & 31, cy = (cidx >> 5) & 31, cz = cidx >> 10;
    float w0 = sh_w[b * 3 + 0], w1 = sh_w[b * 3 + 1], w2 = sh_w[b * 3 + 2];
    const float* b0 = basis;
    const float* b1 = basis + (size_t)LUT_P * 3;
    const float* b2 = basis + (size_t)2 * LUT_P * 3;
    float v[24];   // [ch*8 + c], c = dz*4+dy*2+dx
    float mn = 1e30f, mx = -1e30f;
    #pragma unroll
    for (int s = 0; s < 4; ++s) {             // s = dz*2+dy
        int dz = s >> 1, dy = s & 1;
        size_t o = (size_t)(((cz + dz) * LUT_S + cy + dy) * LUT_S + cx) * 3;
        f4a q0 = *(const f4a*)(b0 + o); f2a r0 = *(const f2a*)(b0 + o + 4);
        f4a q1 = *(const f4a*)(b1 + o); f2a r1 = *(const f2a*)(b1 + o + 4);
        f4a q2 = *(const f4a*)(b2 + o); f2a r2 = *(const f2a*)(b2 + o + 4);
        float vv[6];
        vv[0] = w0 * q0.x + w1 * q1.x + w2 * q2.x;
        vv[1] = w0 * q0.y + w1 * q1.y + w2 * q2.y;
        vv[2] = w0 * q0.z + w1 * q1.z + w2 * q2.z;
        vv[3] = w0 * q0.w + w1 * q1.w + w2 * q2.w;
        vv[4] = w0 * r0.x + w1 * r1.x + w2 * r2.x;
        vv[5] = w0 * r0.y + w1 * r1.y + w2 * r2.y;
        #pragma unroll
        for (int dx = 0; dx < 2; ++dx)
            #pragma unroll
            for (int ch = 0; ch < 3; ++ch) {
                float val = vv[dx * 3 + ch];
                v[ch * 8 + dz * 4 + dy * 2 + dx] = val;
                mn = fminf(mn, val); mx = fmaxf(mx, val);
            }
    }
    float range = mx - mn;
    float inv = (range > 1e-20f) ? 255.0f / range : 0.0f;
    float scale = range * (1.0f / 255.0f);
    unsigned int d[6];
    #pragma unroll
    for (int k = 0; k < 6; ++k) {
        unsigned int pk = 0;
        #pragma unroll
        for (int j = 0; j < 4; ++j) {
            float q = (v[k * 4 + j] - mn) * inv;
            int qi = (int)rintf(q);
            qi = qi < 0 ? 0 : (qi > 255 ? 255 : qi);
            pk |= ((unsigned int)qi) << (8 * j);
        }
        d[k] = pk;
    }
    uint4* outp = cells + ((size_t)e << 1);
    outp[0] = make_uint4(d[0], d[1], d[2], d[3]);
    outp[1] = make_uint4(d[4], d[5], __float_as_uint(scale), __float_as_uint(mn));
}

// ---------------- Kernel F: apply LUT via u8 cell records, 4 px / thread ----
// (unchanged from round 4 — control group for counters)
__device__ __forceinline__ float trilerp_u8(unsigned int lo, unsigned int hi,
                                            float fx, float fy, float fz) {
    float q000 = (float)(lo & 0xffu);
    float q100 = (float)((lo >> 8) & 0xffu);
    float q010 = (float)((lo >> 16) & 0xffu);
    float q110 = (float)((lo >> 24) & 0xffu);
    float q001 = (float)(hi & 0xffu);
    float q101 = (float)((hi >> 8) & 0xffu);
    float q011 = (float)((hi >> 16) & 0xffu);
    float q111 = (float)((hi >> 24) & 0xffu);
    float a0 = q000 + fx * (q100 - q000);
    float a1 = q010 + fx * (q110 - q010);
    float b0 = q001 + fx * (q101 - q001);
    float b1 = q011 + fx * (q111 - q011);
    float c0 = a0 + fy * (a1 - a0);
    float c1 = b0 + fy * (b1 - b0);
    return c0 + fz * (c1 - c0);
}

__global__ __launch_bounds__(256)
void apply_lut_kernel(const float* __restrict__ img,
                      const uint4* __restrict__ cells,
                      float* __restrict__ out, int total_quads, int nblk) {
    const int P  = IMG_H * IMG_W;       // 2,073,600
    const int QP = P / 4;               // 518,400
    // ---- bijective XCD swizzle (m204): XCD k gets a contiguous block range
    int orig = blockIdx.x;
    int qd = nblk >> 3, rm = nblk & 7;
    int xcd = orig & 7, idx = orig >> 3;
    int base = (xcd < rm) ? xcd * (qd + 1) : rm * (qd + 1) + (xcd - rm) * qd;
    int bid = base + idx;
    int t = bid * 256 + (int)threadIdx.x;
    if (t >= total_quads) return;
    int b = t / QP;
    int q = t - b * QP;
    const uint4* cbase = cells + ((size_t)b * CELLS << 1);
    size_t base_e = (size_t)b * 3 * P + (size_t)q * 4;
    f4 R  = __builtin_nontemporal_load((const f4*)(img + base_e));
    f4 G  = __builtin_nontemporal_load((const f4*)(img + base_e + P));
    f4 Bl = __builtin_nontemporal_load((const f4*)(img + base_e + 2 * (size_t)P));

    int cidx[4]; float fx[4], fy[4], fz[4];
    #pragma unroll
    for (int k = 0; k < 4; ++k) {
        float pr = fminf(fmaxf(R[k], 0.f), 1.f) * (float)(LUT_S - 1);
        float pg = fminf(fmaxf(G[k], 0.f), 1.f) * (float)(LUT_S - 1);
        float pb = fminf(fmaxf(Bl[k], 0.f), 1.f) * (float)(LUT_S - 1);
        int ix = (int)pr; if (ix > LUT_S - 2) ix = LUT_S - 2;
        int iy = (int)pg; if (iy > LUT_S - 2) iy = LUT_S - 2;
        int iz = (int)pb; if (iz > LUT_S - 2) iz = LUT_S - 2;
        fx[k] = pr - (float)ix;
        fy[k] = pg - (float)iy;
        fz[k] = pb - (float)iz;
        cidx[k] = (iz << 10) | (iy << 5) | ix;   // x<-R, y<-G, z<-B
    }
    // Issue all 8 gathers before consuming any (memory-level parallelism).
    uint4 A[4], Bq[4];
    #pragma unroll
    for (int k = 0; k < 4; ++k) {
        const uint4* cp = cbase + ((size_t)cidx[k] << 1);
        A[k]  = cp[0];
        Bq[k] = cp[1];
    }
    f4 Ro, Go, Bo;
    #pragma unroll
    for (int k = 0; k < 4; ++k) {
        float scale = __uint_as_float(Bq[k].z);
        float offs  = __uint_as_float(Bq[k].w);
        float tr = trilerp_u8(A[k].x, A[k].y, fx[k], fy[k], fz[k]);
        float tg = trilerp_u8(A[k].z, A[k].w, fx[k], fy[k], fz[k]);
        float tb = trilerp_u8(Bq[k].x, Bq[k].y, fx[k], fy[k], fz[k]);
        Ro[k] = fminf(fmaxf(tr * scale + offs, 0.f), 1.f);
        Go[k] = fminf(fmaxf(tg * scale + offs, 0.f), 1.f);
        Bo[k] = fminf(fmaxf(tb * scale + offs, 0.f), 1.f);
    }
    __builtin_nontemporal_store(Ro, (f4*)(out + base_e));
    __builtin_nontemporal_store(Go, (f4*)(out + base_e + P));
    __builtin_nontemporal_store(Bo, (f4*)(out + base_e + 2 * (size_t)P));
}

extern "C" void kernel_launch(void* const* d_in, const int* in_sizes, int n_in,
                              void* d_out, int out_size, void* d_ws, size_t ws_size,
                              hipStream_t stream) {
    const float* img     = (const float*)d_in[0];
    const float* basis   = (const float*)d_in[1];
    const float* conv1_w = (const float*)d_in[2];
    const float* conv1_b = (const float*)d_in[3];
    const float* conv2_w = (const float*)d_in[4];
    const float* conv2_b = (const float*)d_in[5];
    const float* dense_w = (const float*)d_in[6];
    const float* dense_b = (const float*)d_in[7];
    float* out = (float*)d_out;

    const size_t P = (size_t)IMG_H * IMG_W;
    int B = (int)(in_sizes[0] / (3 * P));   // 4

    // workspace layout (floats)
    float* ws = (float*)d_ws;
    size_t off = 0;
    float* tmp1    = ws + off; off += (size_t)B * 3 * IMG_H * TW;
    float* thumb   = ws + off; off += (size_t)B * 3 * TH * TW;
    float* c1      = ws + off; off += (size_t)B * 16 * 128 * 128;
    float* partial = ws + off; off += (size_t)B * 32 * 64;
    off = (off + 3) & ~(size_t)3;                                  // 16B align
    uint4* cells   = (uint4*)(ws + off); off += (size_t)B * CELLS * 8;

    const int TPB = 256;
    {   // A: W-resize (one block per row)
        resize_w_kernel<<<B * 3 * IMG_H, TPB, 0, stream>>>(img, tmp1);
    }
    {   // B: H-resize
        int total = B * 3 * TH * TW;
        resize_h_kernel<<<(total + TPB - 1) / TPB, TPB, 0, stream>>>(tmp1, thumb, total);
    }
    {   // C1: 4 oc / thread, 4 groups
        int total = B * 4 * 128 * 128;
        conv1_kernel<<<(total + TPB - 1) / TPB, TPB, 0, stream>>>(thumb, conv1_w, conv1_b, c1, total);
    }
    {   // C2 + pool: 2 oc / thread, 16 groups
        int total = B * 16 * 4096;
        conv2_pool_kernel<<<(total + TPB - 1) / TPB, TPB, 0, stream>>>(c1, conv2_w, conv2_b, partial, total);
    }
    {   // E: fused head + blend -> u8 cell records (vectorized)
        int total = B * CELLS;
        blend_cells_kernel<<<(total + TPB - 1) / TPB, TPB, 0, stream>>>(
            basis, partial, dense_w, dense_b, cells, B, total);
    }
    {   // F: apply (XCD-swizzled)
        int total = B * (int)(P / 4);
        int nblk = (total + TPB - 1) / TPB;
        apply_lut_kernel<<<nblk, TPB, 0, stream>>>(img, cells, out, total, nblk);
    }
}